// Round 3
// baseline (229.754 us; speedup 1.0000x reference)
//
#include <hip/hip_runtime.h>
#include <math.h>

// Problem constants (fixed by setup_inputs)
constexpr int BS = 16;
constexpr int NA = 8400;    // 80^2 + 40^2 + 20^2, strides 8/16/32
constexpr int NC = 80;
constexpr int MG = 128;
constexpr int TK = 13;
constexpr int NCAND = 1536; // max enumerated inside-candidates ~1251 (box<200^2, +-2 cells)
constexpr int QCAP = 32768; // fg selections <= BS*MG*TK = 26624

// Output layout (floats), return order: labels, bboxes, scores, fg_mask, tgt_idx
constexpr int OFF_LBL = 0;
constexpr int OFF_BB  = OFF_LBL + BS * NA;
constexpr int OFF_SC  = OFF_BB  + BS * NA * 4;
constexpr int OFF_FG  = OFF_SC  + BS * NA * NC;
constexpr int OFF_TG  = OFF_FG  + BS * NA;

__device__ __forceinline__ float ciou_f(float gx, float gy, float gz, float gw,
                                        float px, float py, float pz, float pw) {
    const float eps = 1e-7f;
    float w1 = gz - gx, h1 = gw - gy + eps;
    float w2 = pz - px, h2 = pw - py + eps;
    float iw = fmaxf(fminf(gz, pz) - fmaxf(gx, px), 0.f);
    float ih = fmaxf(fminf(gw, pw) - fmaxf(gy, py), 0.f);
    float inter = iw * ih;
    float uni = w1 * h1 + w2 * h2 - inter + eps;
    float iou = inter / uni;
    float cw = fmaxf(gz, pz) - fminf(gx, px);
    float ch = fmaxf(gw, pw) - fminf(gy, py);
    float c2 = cw * cw + ch * ch + eps;
    float dx = px + pz - gx - gz;
    float dy = py + pw - gy - gw;
    float rho2 = (dx * dx + dy * dy) * 0.25f;
    float dat = atanf(w2 / h2) - atanf(w1 / h1);
    float v = 0.4052847345693511f * dat * dat;   // 4/pi^2
    float alpha = v / (v - iou + (1.f + eps));
    return iou - (rho2 / c2 + v * alpha);
}

__device__ __forceinline__ bool inside_gt(float ax, float ay,
                                          float gx, float gy, float gz, float gw) {
    float d = fminf(fminf(ax - gx, ay - gy), fminf(gz - ax, gw - ay));
    return d > 1e-9f;
}

// K1: one WAVE per (b,m). Enumerate candidate anchors from the box's grid
// rectangles (3 levels), compact positives to LDS, 13 shuffle-argmax rounds
// (exact lax.top_k semantics: lowest-index ties + npos<13 zero-fill).
__global__ __launch_bounds__(64) void k_topk(
    const float* __restrict__ pd_scores, const float* __restrict__ pd_bboxes,
    const int* __restrict__ gt_labels, const float* __restrict__ gt_bboxes,
    const float* __restrict__ mask_gt,
    int* __restrict__ fg_cnt, int* __restrict__ fg_m)
{
    __shared__ float cv[NCAND];
    __shared__ int   ca[NCAND];
    __shared__ int   s_cnt;
    __shared__ unsigned s_pm;           // "align>0" mask for anchors 0..31

    int bm = blockIdx.x;
    if (mask_gt[bm] <= 0.f) return;
    int b = bm >> 7;                    // MG = 128
    int m = bm & (MG - 1);
    int tid = threadIdx.x;

    if (tid == 0) { s_cnt = 0; s_pm = 0u; }
    __syncthreads();

    const float4 g = *reinterpret_cast<const float4*>(gt_bboxes + bm * 4);
    const int lbl = gt_labels[bm];
    const float* pbb = pd_bboxes + (size_t)b * NA * 4;
    const float* psc = pd_scores + (size_t)b * NA * NC;

    auto do_level = [&](float s, int n, int base) {
        // conservative rectangle (+-1 extra cell for float-rounding safety);
        // exact inside_gt test per candidate makes the set bitwise-identical.
        int xlo = max(0, (int)floorf(g.x / s - 0.5f) - 1);
        int xhi = min(n - 1, (int)ceilf(g.z / s - 0.5f) + 1);
        int ylo = max(0, (int)floorf(g.y / s - 0.5f) - 1);
        int yhi = min(n - 1, (int)ceilf(g.w / s - 0.5f) + 1);
        int w = xhi - xlo + 1, h = yhi - ylo + 1;
        if (w <= 0 || h <= 0) return;
        int cnt = w * h;
        for (int idx = tid; idx < cnt; idx += 64) {
            int iy = ylo + idx / w;
            int ix = xlo + idx - (idx / w) * w;
            float ax = (ix + 0.5f) * s;          // bitwise == anc[] (pow2 scale)
            float ay = (iy + 0.5f) * s;
            if (!inside_gt(ax, ay, g.x, g.y, g.z, g.w)) continue;
            int a = base + iy * n + ix;
            float4 p = *reinterpret_cast<const float4*>(pbb + (size_t)a * 4);
            float ov = fmaxf(ciou_f(g.x, g.y, g.z, g.w, p.x, p.y, p.z, p.w), 0.f);
            float sc = psc[(size_t)a * NC + lbl];
            float ov2 = ov * ov;
            float al = sc * ov2 * ov2 * ov2;     // score^1 * ov^6
            if (al > 0.f) {
                int slot = atomicAdd(&s_cnt, 1);
                if (slot < NCAND) { cv[slot] = al; ca[slot] = a; }
                if (a < 32) atomicOr(&s_pm, 1u << a);
            }
        }
    };
    do_level(8.f, 80, 0);
    do_level(16.f, 40, 6400);
    do_level(32.f, 20, 8000);
    __syncthreads();

    int npos = min(s_cnt, NCAND);
    int rounds = min(npos, TK);
    int* fgc = fg_cnt + b * NA;
    int* fgm = fg_m + b * NA;

    for (int k = 0; k < rounds; ++k) {
        float bv = -1.f; int bk = 0x7fffffff;
        for (int p = tid; p < npos; p += 64) {
            float v = cv[p];
            int key = (ca[p] << 11) | p;         // anchor high bits: ties -> lowest anchor
            if (v > bv || (v == bv && key < bk)) { bv = v; bk = key; }
        }
        #pragma unroll
        for (int off = 32; off > 0; off >>= 1) {
            float v2 = __shfl_down(bv, off);
            int   k2 = __shfl_down(bk, off);
            if (v2 > bv || (v2 == bv && k2 < bk)) { bv = v2; bk = k2; }
        }
        if (tid == 0) {
            int slot = bk & 2047;
            int a = bk >> 11;
            cv[slot] = -1.f;                     // remove winner
            atomicAdd(&fgc[a], 1);
            fgm[a] = m;                          // unique writer when final cnt==1
        }
        __syncthreads();
    }

    // npos < TK: top_k pads with globally lowest-index zero-valued anchors
    // (indices provably < 26 < 32); mask_in_gts then filters them.
    if (tid == 0) {
        int need = TK - rounds;
        unsigned pm = s_pm;
        for (int idx = 0; idx < 32 && need > 0; ++idx) {
            if (!((pm >> idx) & 1u)) {
                float ax = (idx + 0.5f) * 8.f, ay = 4.f;
                if (inside_gt(ax, ay, g.x, g.y, g.z, g.w)) {
                    atomicAdd(&fgc[idx], 1);
                    fgm[idx] = m;
                }
                --need;
            }
        }
    }
}

// K2: per anchor. cnt<=1 resolved inline; cnt>1 queued for k_fix.
__global__ __launch_bounds__(256) void k_assign(
    const float* __restrict__ pd_scores, const float* __restrict__ pd_bboxes,
    const float* __restrict__ anc, const int* __restrict__ gt_labels,
    const float* __restrict__ gt_bboxes, const float* __restrict__ mask_gt,
    const int* __restrict__ fg_cnt, const int* __restrict__ fg_m,
    float* __restrict__ out, float* __restrict__ am_ws,
    int* __restrict__ gi_ws, int* __restrict__ lbl_ws,
    unsigned* __restrict__ pos_am, unsigned* __restrict__ pos_ov,
    int* __restrict__ multi_cnt, int* __restrict__ multi_q,
    int* __restrict__ fgq_cnt, int* __restrict__ fgq)
{
    int i = blockIdx.x * 256 + threadIdx.x;
    if (i >= BS * NA) return;
    int cnt = fg_cnt[i];
    if (cnt > 1) {                       // rare: resolved by k_fix
        int q = atomicAdd(multi_cnt, 1);
        multi_q[q] = i;
        return;
    }
    int b = i / NA, a = i - b * NA;
    int t = (cnt == 1) ? fg_m[i] : 0;
    int gi = b * MG + t;
    float4 g = *reinterpret_cast<const float4*>(gt_bboxes + gi * 4);
    int lraw = gt_labels[gi];
    int lbl = max(lraw, 0);

    if (cnt == 1) {
        float am = 0.f, ovv = 0.f;
        if (mask_gt[gi] > 0.f) {
            float ax = anc[2 * a], ay = anc[2 * a + 1];
            if (inside_gt(ax, ay, g.x, g.y, g.z, g.w)) {
                float4 p = *reinterpret_cast<const float4*>(pd_bboxes + (size_t)i * 4);
                float ov = fmaxf(ciou_f(g.x, g.y, g.z, g.w, p.x, p.y, p.z, p.w), 0.f);
                float sc = pd_scores[(size_t)i * NC + lraw];
                float ov2 = ov * ov;
                am = sc * ov2 * ov2 * ov2;
                ovv = ov;
            }
        }
        atomicMax(&pos_am[gi], __float_as_uint(am));
        atomicMax(&pos_ov[gi], __float_as_uint(ovv));
        am_ws[i] = am; gi_ws[i] = gi; lbl_ws[i] = lbl;
        int q = atomicAdd(fgq_cnt, 1);
        fgq[q] = i;
    }

    out[OFF_LBL + i] = (float)lbl;
    reinterpret_cast<float4*>(out + OFF_BB)[i] = g;
    out[OFF_FG + i] = cnt ? 1.f : 0.f;
    out[OFF_TG + i] = (float)t;
}

// K3: one wave per multi-assigned anchor — argmax over 128 masked overlaps
// (2 per lane + shuffle reduce, first-max tie-break), write its outputs.
__global__ __launch_bounds__(256) void k_fix(
    const float* __restrict__ pd_scores, const float* __restrict__ pd_bboxes,
    const float* __restrict__ anc, const int* __restrict__ gt_labels,
    const float* __restrict__ gt_bboxes, const float* __restrict__ mask_gt,
    const int* __restrict__ multi_cnt, const int* __restrict__ multi_q,
    float* __restrict__ out, float* __restrict__ am_ws,
    int* __restrict__ gi_ws, int* __restrict__ lbl_ws,
    unsigned* __restrict__ pos_am, unsigned* __restrict__ pos_ov,
    int* __restrict__ fgq_cnt, int* __restrict__ fgq)
{
    int gtid = blockIdx.x * 256 + threadIdx.x;
    int wave = gtid >> 6;
    int lane = gtid & 63;
    int nwaves = (gridDim.x * 256) >> 6;
    int qn = *multi_cnt;

    for (int qi = wave; qi < qn; qi += nwaves) {
        int i = multi_q[qi];
        int b = i / NA, a = i - b * NA;
        float ax = anc[2 * a], ay = anc[2 * a + 1];
        float4 p = *reinterpret_cast<const float4*>(pd_bboxes + (size_t)i * 4);

        auto ovm = [&](int mm) -> float {
            int gi = b * MG + mm;
            float ov = 0.f;
            if (mask_gt[gi] > 0.f) {
                float4 gg = *reinterpret_cast<const float4*>(gt_bboxes + gi * 4);
                if (inside_gt(ax, ay, gg.x, gg.y, gg.z, gg.w))
                    ov = fmaxf(ciou_f(gg.x, gg.y, gg.z, gg.w, p.x, p.y, p.z, p.w), 0.f);
            }
            return ov;
        };
        float ov0 = ovm(lane);
        float ov1 = ovm(lane + 64);
        float bov; int bm_;
        if (ov1 > ov0) { bov = ov1; bm_ = lane + 64; }
        else           { bov = ov0; bm_ = lane; }
        #pragma unroll
        for (int off = 32; off > 0; off >>= 1) {
            float v2 = __shfl_down(bov, off);
            int   m2 = __shfl_down(bm_, off);
            if (v2 > bov || (v2 == bov && m2 < bm_)) { bov = v2; bm_ = m2; }
        }
        if (lane == 0) {
            int t = bm_;
            int gi = b * MG + t;
            int lraw = gt_labels[gi];
            int lbl = max(lraw, 0);
            float am = 0.f;
            if (bov > 0.f) {                     // bov>0 implies mask&&inside at t
                float sc = pd_scores[(size_t)i * NC + lraw];
                float o2 = bov * bov;
                am = sc * o2 * o2 * o2;
            }
            atomicMax(&pos_am[gi], __float_as_uint(am));
            atomicMax(&pos_ov[gi], __float_as_uint(bov));
            float4 g = *reinterpret_cast<const float4*>(gt_bboxes + gi * 4);
            out[OFF_LBL + i] = (float)lbl;
            reinterpret_cast<float4*>(out + OFF_BB)[i] = g;
            out[OFF_FG + i] = 1.f;
            out[OFF_TG + i] = (float)t;
            am_ws[i] = am; gi_ws[i] = gi; lbl_ws[i] = lbl;
            int q = atomicAdd(fgq_cnt, 1);
            fgq[q] = i;
        }
    }
}

// K4: scatter norm into the (pre-zeroed) scores tensor — one 4B store per fg anchor.
__global__ __launch_bounds__(256) void k_scatter(
    const int* __restrict__ fgq_cnt, const int* __restrict__ fgq,
    const float* __restrict__ am_ws, const int* __restrict__ gi_ws,
    const int* __restrict__ lbl_ws,
    const unsigned* __restrict__ pos_am, const unsigned* __restrict__ pos_ov,
    float* __restrict__ out_scores)
{
    int n = *fgq_cnt;
    for (int idx = blockIdx.x * 256 + threadIdx.x; idx < n; idx += gridDim.x * 256) {
        int i = fgq[idx];
        int gi = gi_ws[i];
        float norm = am_ws[i] * __uint_as_float(pos_ov[gi]) /
                     (__uint_as_float(pos_am[gi]) + 1e-9f);
        out_scores[(size_t)i * NC + lbl_ws[i]] = norm;
    }
}

extern "C" void kernel_launch(void* const* d_in, const int* in_sizes, int n_in,
                              void* d_out, int out_size, void* d_ws, size_t ws_size,
                              hipStream_t stream) {
    const float* pd_scores = (const float*)d_in[0];
    const float* pd_bboxes = (const float*)d_in[1];
    const float* anc       = (const float*)d_in[2];
    const int*   gt_labels = (const int*)d_in[3];
    const float* gt_bboxes = (const float*)d_in[4];
    const float* mask_gt   = (const float*)d_in[5];
    float* out = (float*)d_out;

    // Workspace carve. Zeroed region first.
    unsigned char* w = (unsigned char*)d_ws;
    size_t off = 0;
    int*      fg_cnt    = (int*)(w + off);      off += (size_t)BS * NA * 4;
    unsigned* pos_am    = (unsigned*)(w + off); off += (size_t)BS * MG * 4;
    unsigned* pos_ov    = (unsigned*)(w + off); off += (size_t)BS * MG * 4;
    int*      multi_cnt = (int*)(w + off);      off += 4;
    int*      fgq_cnt   = (int*)(w + off);      off += 4;
    size_t zero_bytes = off;
    int*      fg_m      = (int*)(w + off);      off += (size_t)BS * NA * 4;
    float*    am_ws     = (float*)(w + off);    off += (size_t)BS * NA * 4;
    int*      gi_ws     = (int*)(w + off);      off += (size_t)BS * NA * 4;
    int*      lbl_ws    = (int*)(w + off);      off += (size_t)BS * NA * 4;
    int*      multi_q   = (int*)(w + off);      off += (size_t)QCAP * 4;
    int*      fgq       = (int*)(w + off);      off += (size_t)QCAP * 4;

    hipMemsetAsync(w, 0, zero_bytes, stream);
    hipMemsetAsync(out + OFF_SC, 0, (size_t)BS * NA * NC * sizeof(float), stream);

    k_topk<<<BS * MG, 64, 0, stream>>>(pd_scores, pd_bboxes, gt_labels,
                                       gt_bboxes, mask_gt, fg_cnt, fg_m);

    int nA = BS * NA;
    k_assign<<<(nA + 255) / 256, 256, 0, stream>>>(
        pd_scores, pd_bboxes, anc, gt_labels, gt_bboxes, mask_gt,
        fg_cnt, fg_m, out, am_ws, gi_ws, lbl_ws, pos_am, pos_ov,
        multi_cnt, multi_q, fgq_cnt, fgq);

    k_fix<<<64, 256, 0, stream>>>(
        pd_scores, pd_bboxes, anc, gt_labels, gt_bboxes, mask_gt,
        multi_cnt, multi_q, out, am_ws, gi_ws, lbl_ws, pos_am, pos_ov,
        fgq_cnt, fgq);

    k_scatter<<<128, 256, 0, stream>>>(fgq_cnt, fgq, am_ws, gi_ws, lbl_ws,
                                       pos_am, pos_ov, out + OFF_SC);
}

// Round 4
// 224.951 us; speedup vs baseline: 1.0214x; 1.0214x over previous
//
#include <hip/hip_runtime.h>
#include <math.h>

// Problem constants (fixed by setup_inputs)
constexpr int BS = 16;
constexpr int NA = 8400;    // 80^2 + 40^2 + 20^2, strides 8/16/32
constexpr int NC = 80;
constexpr int MG = 128;
constexpr int TK = 13;
constexpr int NCAND = 1536; // max enumerated inside-candidates ~1251 (box<200^2, +-2 cells)
constexpr int QCAP = 65536; // multi/fg queues (multi observed ~23K; fg <= BS*MG*TK=26624)

// Output layout (floats), return order: labels, bboxes, scores, fg_mask, tgt_idx
constexpr int OFF_LBL = 0;
constexpr int OFF_BB  = OFF_LBL + BS * NA;
constexpr int OFF_SC  = OFF_BB  + BS * NA * 4;
constexpr int OFF_FG  = OFF_SC  + BS * NA * NC;
constexpr int OFF_TG  = OFF_FG  + BS * NA;

// CIoU with the arctan difference supplied by the caller (lets hot loops hoist
// the loop-invariant atanf). dat = atanf(w2/h2) - atanf(w1/h1) with
// w1=gz-gx, h1=gw-gy+eps, w2=pz-px, h2=pw-py+eps.
__device__ __forceinline__ float ciou_pre(float gx, float gy, float gz, float gw,
                                          float px, float py, float pz, float pw,
                                          float dat) {
    const float eps = 1e-7f;
    float w1 = gz - gx, h1 = gw - gy + eps;
    float w2 = pz - px, h2 = pw - py + eps;
    float iw = fmaxf(fminf(gz, pz) - fmaxf(gx, px), 0.f);
    float ih = fmaxf(fminf(gw, pw) - fmaxf(gy, py), 0.f);
    float inter = iw * ih;
    float uni = w1 * h1 + w2 * h2 - inter + eps;
    float iou = inter / uni;
    float cw = fmaxf(gz, pz) - fminf(gx, px);
    float ch = fmaxf(gw, pw) - fminf(gy, py);
    float c2 = cw * cw + ch * ch + eps;
    float dx = px + pz - gx - gz;
    float dy = py + pw - gy - gw;
    float rho2 = (dx * dx + dy * dy) * 0.25f;
    float v = 0.4052847345693511f * dat * dat;   // 4/pi^2
    float alpha = v / (v - iou + (1.f + eps));
    return iou - (rho2 / c2 + v * alpha);
}

__device__ __forceinline__ float ciou_f(float gx, float gy, float gz, float gw,
                                        float px, float py, float pz, float pw) {
    const float eps = 1e-7f;
    float dat = atanf((pz - px) / (pw - py + eps)) - atanf((gz - gx) / (gw - gy + eps));
    return ciou_pre(gx, gy, gz, gw, px, py, pz, pw, dat);
}

__device__ __forceinline__ bool inside_gt(float ax, float ay,
                                          float gx, float gy, float gz, float gw) {
    float d = fminf(fminf(ax - gx, ay - gy), fminf(gz - ax, gw - ay));
    return d > 1e-9f;
}

// K1: one WAVE per (b,m). Enumerate candidate anchors from the box's grid
// rectangles (3 levels), compact positives to LDS, 13 shuffle-argmax rounds
// (exact lax.top_k semantics: lowest-index ties + npos<13 zero-fill).
__global__ __launch_bounds__(64) void k_topk(
    const float* __restrict__ pd_scores, const float* __restrict__ pd_bboxes,
    const int* __restrict__ gt_labels, const float* __restrict__ gt_bboxes,
    const float* __restrict__ mask_gt,
    int* __restrict__ fg_cnt, int* __restrict__ fg_m)
{
    __shared__ float cv[NCAND];
    __shared__ int   ca[NCAND];
    __shared__ int   s_cnt;
    __shared__ unsigned s_pm;           // "align>0" mask for anchors 0..31

    int bm = blockIdx.x;
    if (mask_gt[bm] <= 0.f) return;
    int b = bm >> 7;                    // MG = 128
    int m = bm & (MG - 1);
    int tid = threadIdx.x;

    if (tid == 0) { s_cnt = 0; s_pm = 0u; }
    __syncthreads();

    const float4 g = *reinterpret_cast<const float4*>(gt_bboxes + bm * 4);
    const int lbl = gt_labels[bm];
    const float* pbb = pd_bboxes + (size_t)b * NA * 4;
    const float* psc = pd_scores + (size_t)b * NA * NC;
    const float at_g = atanf((g.z - g.x) / (g.w - g.y + 1e-7f));  // block-invariant

    auto do_level = [&](float s, int n, int base) {
        // conservative rectangle (+-1 extra cell for float-rounding safety);
        // exact inside_gt test per candidate makes the set bitwise-identical.
        int xlo = max(0, (int)floorf(g.x / s - 0.5f) - 1);
        int xhi = min(n - 1, (int)ceilf(g.z / s - 0.5f) + 1);
        int ylo = max(0, (int)floorf(g.y / s - 0.5f) - 1);
        int yhi = min(n - 1, (int)ceilf(g.w / s - 0.5f) + 1);
        int w = xhi - xlo + 1, h = yhi - ylo + 1;
        if (w <= 0 || h <= 0) return;
        int cnt = w * h;
        for (int idx = tid; idx < cnt; idx += 64) {
            int iy = ylo + idx / w;
            int ix = xlo + idx - (idx / w) * w;
            float ax = (ix + 0.5f) * s;          // bitwise == anc[] (pow2 scale)
            float ay = (iy + 0.5f) * s;
            if (!inside_gt(ax, ay, g.x, g.y, g.z, g.w)) continue;
            int a = base + iy * n + ix;
            float4 p = *reinterpret_cast<const float4*>(pbb + (size_t)a * 4);
            float dat = atanf((p.z - p.x) / (p.w - p.y + 1e-7f)) - at_g;
            float ov = fmaxf(ciou_pre(g.x, g.y, g.z, g.w, p.x, p.y, p.z, p.w, dat), 0.f);
            float sc = psc[(size_t)a * NC + lbl];
            float ov2 = ov * ov;
            float al = sc * ov2 * ov2 * ov2;     // score^1 * ov^6
            if (al > 0.f) {
                int slot = atomicAdd(&s_cnt, 1);
                if (slot < NCAND) { cv[slot] = al; ca[slot] = a; }
                if (a < 32) atomicOr(&s_pm, 1u << a);
            }
        }
    };
    do_level(8.f, 80, 0);
    do_level(16.f, 40, 6400);
    do_level(32.f, 20, 8000);
    __syncthreads();

    int npos = min(s_cnt, NCAND);
    int rounds = min(npos, TK);
    int* fgc = fg_cnt + b * NA;
    int* fgm = fg_m + b * NA;

    for (int k = 0; k < rounds; ++k) {
        float bv = -1.f; int bk = 0x7fffffff;
        for (int p = tid; p < npos; p += 64) {
            float v = cv[p];
            int key = (ca[p] << 11) | p;         // anchor high bits: ties -> lowest anchor
            if (v > bv || (v == bv && key < bk)) { bv = v; bk = key; }
        }
        #pragma unroll
        for (int off = 32; off > 0; off >>= 1) {
            float v2 = __shfl_down(bv, off);
            int   k2 = __shfl_down(bk, off);
            if (v2 > bv || (v2 == bv && k2 < bk)) { bv = v2; bk = k2; }
        }
        if (tid == 0) {
            int slot = bk & 2047;
            int a = bk >> 11;
            cv[slot] = -1.f;                     // remove winner
            atomicAdd(&fgc[a], 1);
            fgm[a] = m;                          // unique writer when final cnt==1
        }
        __syncthreads();
    }

    // npos < TK: top_k pads with globally lowest-index zero-valued anchors
    // (indices provably < 26 < 32); mask_in_gts then filters them.
    if (tid == 0) {
        int need = TK - rounds;
        unsigned pm = s_pm;
        for (int idx = 0; idx < 32 && need > 0; ++idx) {
            if (!((pm >> idx) & 1u)) {
                float ax = (idx + 0.5f) * 8.f, ay = 4.f;
                if (inside_gt(ax, ay, g.x, g.y, g.z, g.w)) {
                    atomicAdd(&fgc[idx], 1);
                    fgm[idx] = m;
                }
                --need;
            }
        }
    }
}

// K2: per anchor. cnt<=1 resolved inline; cnt>1 queued for k_fix.
__global__ __launch_bounds__(256) void k_assign(
    const float* __restrict__ pd_scores, const float* __restrict__ pd_bboxes,
    const float* __restrict__ anc, const int* __restrict__ gt_labels,
    const float* __restrict__ gt_bboxes, const float* __restrict__ mask_gt,
    const int* __restrict__ fg_cnt, const int* __restrict__ fg_m,
    float* __restrict__ out, float* __restrict__ am_ws,
    int* __restrict__ gi_ws, int* __restrict__ lbl_ws,
    unsigned* __restrict__ pos_am, unsigned* __restrict__ pos_ov,
    int* __restrict__ multi_cnt, int* __restrict__ multi_q,
    int* __restrict__ fgq_cnt, int* __restrict__ fgq)
{
    int i = blockIdx.x * 256 + threadIdx.x;
    if (i >= BS * NA) return;
    int cnt = fg_cnt[i];
    if (cnt > 1) {                       // resolved by k_fix
        int q = atomicAdd(multi_cnt, 1);
        multi_q[q] = i;
        return;
    }
    int b = i / NA, a = i - b * NA;
    int t = (cnt == 1) ? fg_m[i] : 0;
    int gi = b * MG + t;
    float4 g = *reinterpret_cast<const float4*>(gt_bboxes + gi * 4);
    int lraw = gt_labels[gi];
    int lbl = max(lraw, 0);

    if (cnt == 1) {
        float am = 0.f, ovv = 0.f;
        if (mask_gt[gi] > 0.f) {
            float ax = anc[2 * a], ay = anc[2 * a + 1];
            if (inside_gt(ax, ay, g.x, g.y, g.z, g.w)) {
                float4 p = *reinterpret_cast<const float4*>(pd_bboxes + (size_t)i * 4);
                float ov = fmaxf(ciou_f(g.x, g.y, g.z, g.w, p.x, p.y, p.z, p.w), 0.f);
                float sc = pd_scores[(size_t)i * NC + lraw];
                float ov2 = ov * ov;
                am = sc * ov2 * ov2 * ov2;
                ovv = ov;
            }
        }
        atomicMax(&pos_am[gi], __float_as_uint(am));
        atomicMax(&pos_ov[gi], __float_as_uint(ovv));
        am_ws[i] = am; gi_ws[i] = gi; lbl_ws[i] = lbl;
        int q = atomicAdd(fgq_cnt, 1);
        fgq[q] = i;
    }

    out[OFF_LBL + i] = (float)lbl;
    reinterpret_cast<float4*>(out + OFF_BB)[i] = g;
    out[OFF_FG + i] = cnt ? 1.f : 0.f;
    out[OFF_TG + i] = (float)t;
}

// K3: one wave per multi-assigned anchor — argmax over 128 masked overlaps
// (2 per lane + shuffle reduce, first-max tie-break), write its outputs.
__global__ __launch_bounds__(256) void k_fix(
    const float* __restrict__ pd_scores, const float* __restrict__ pd_bboxes,
    const float* __restrict__ anc, const int* __restrict__ gt_labels,
    const float* __restrict__ gt_bboxes, const float* __restrict__ mask_gt,
    const int* __restrict__ multi_cnt, const int* __restrict__ multi_q,
    float* __restrict__ out, float* __restrict__ am_ws,
    int* __restrict__ gi_ws, int* __restrict__ lbl_ws,
    unsigned* __restrict__ pos_am, unsigned* __restrict__ pos_ov,
    int* __restrict__ fgq_cnt, int* __restrict__ fgq)
{
    int gtid = blockIdx.x * 256 + threadIdx.x;
    int wave = gtid >> 6;
    int lane = gtid & 63;
    int nwaves = (gridDim.x * 256) >> 6;
    int qn = *multi_cnt;

    for (int qi = wave; qi < qn; qi += nwaves) {
        int i = multi_q[qi];
        int b = i / NA, a = i - b * NA;
        float ax = anc[2 * a], ay = anc[2 * a + 1];
        float4 p = *reinterpret_cast<const float4*>(pd_bboxes + (size_t)i * 4);
        float at_p = atanf((p.z - p.x) / (p.w - p.y + 1e-7f));  // anchor-invariant

        auto ovm = [&](int mm) -> float {
            int gi = b * MG + mm;
            float ov = 0.f;
            if (mask_gt[gi] > 0.f) {
                float4 gg = *reinterpret_cast<const float4*>(gt_bboxes + gi * 4);
                if (inside_gt(ax, ay, gg.x, gg.y, gg.z, gg.w)) {
                    float dat = at_p - atanf((gg.z - gg.x) / (gg.w - gg.y + 1e-7f));
                    ov = fmaxf(ciou_pre(gg.x, gg.y, gg.z, gg.w, p.x, p.y, p.z, p.w, dat), 0.f);
                }
            }
            return ov;
        };
        float ov0 = ovm(lane);
        float ov1 = ovm(lane + 64);
        float bov; int bm_;
        if (ov1 > ov0) { bov = ov1; bm_ = lane + 64; }
        else           { bov = ov0; bm_ = lane; }
        #pragma unroll
        for (int off = 32; off > 0; off >>= 1) {
            float v2 = __shfl_down(bov, off);
            int   m2 = __shfl_down(bm_, off);
            if (v2 > bov || (v2 == bov && m2 < bm_)) { bov = v2; bm_ = m2; }
        }
        if (lane == 0) {
            int t = bm_;
            int gi = b * MG + t;
            int lraw = gt_labels[gi];
            int lbl = max(lraw, 0);
            float am = 0.f;
            if (bov > 0.f) {                     // bov>0 implies mask&&inside at t
                float sc = pd_scores[(size_t)i * NC + lraw];
                float o2 = bov * bov;
                am = sc * o2 * o2 * o2;
            }
            atomicMax(&pos_am[gi], __float_as_uint(am));
            atomicMax(&pos_ov[gi], __float_as_uint(bov));
            float4 g = *reinterpret_cast<const float4*>(gt_bboxes + gi * 4);
            out[OFF_LBL + i] = (float)lbl;
            reinterpret_cast<float4*>(out + OFF_BB)[i] = g;
            out[OFF_FG + i] = 1.f;
            out[OFF_TG + i] = (float)t;
            am_ws[i] = am; gi_ws[i] = gi; lbl_ws[i] = lbl;
            int q = atomicAdd(fgq_cnt, 1);
            fgq[q] = i;
        }
    }
}

// K4: scatter norm into the (pre-zeroed) scores tensor — one 4B store per fg anchor.
__global__ __launch_bounds__(256) void k_scatter(
    const int* __restrict__ fgq_cnt, const int* __restrict__ fgq,
    const float* __restrict__ am_ws, const int* __restrict__ gi_ws,
    const int* __restrict__ lbl_ws,
    const unsigned* __restrict__ pos_am, const unsigned* __restrict__ pos_ov,
    float* __restrict__ out_scores)
{
    int n = *fgq_cnt;
    for (int idx = blockIdx.x * 256 + threadIdx.x; idx < n; idx += gridDim.x * 256) {
        int i = fgq[idx];
        int gi = gi_ws[i];
        float norm = am_ws[i] * __uint_as_float(pos_ov[gi]) /
                     (__uint_as_float(pos_am[gi]) + 1e-9f);
        out_scores[(size_t)i * NC + lbl_ws[i]] = norm;
    }
}

extern "C" void kernel_launch(void* const* d_in, const int* in_sizes, int n_in,
                              void* d_out, int out_size, void* d_ws, size_t ws_size,
                              hipStream_t stream) {
    const float* pd_scores = (const float*)d_in[0];
    const float* pd_bboxes = (const float*)d_in[1];
    const float* anc       = (const float*)d_in[2];
    const int*   gt_labels = (const int*)d_in[3];
    const float* gt_bboxes = (const float*)d_in[4];
    const float* mask_gt   = (const float*)d_in[5];
    float* out = (float*)d_out;

    // Workspace carve. Zeroed region first.
    unsigned char* w = (unsigned char*)d_ws;
    size_t off = 0;
    int*      fg_cnt    = (int*)(w + off);      off += (size_t)BS * NA * 4;
    unsigned* pos_am    = (unsigned*)(w + off); off += (size_t)BS * MG * 4;
    unsigned* pos_ov    = (unsigned*)(w + off); off += (size_t)BS * MG * 4;
    int*      multi_cnt = (int*)(w + off);      off += 4;
    int*      fgq_cnt   = (int*)(w + off);      off += 4;
    size_t zero_bytes = off;
    int*      fg_m      = (int*)(w + off);      off += (size_t)BS * NA * 4;
    float*    am_ws     = (float*)(w + off);    off += (size_t)BS * NA * 4;
    int*      gi_ws     = (int*)(w + off);      off += (size_t)BS * NA * 4;
    int*      lbl_ws    = (int*)(w + off);      off += (size_t)BS * NA * 4;
    int*      multi_q   = (int*)(w + off);      off += (size_t)QCAP * 4;
    int*      fgq       = (int*)(w + off);      off += (size_t)QCAP * 4;

    hipMemsetAsync(w, 0, zero_bytes, stream);
    hipMemsetAsync(out + OFF_SC, 0, (size_t)BS * NA * NC * sizeof(float), stream);

    k_topk<<<BS * MG, 64, 0, stream>>>(pd_scores, pd_bboxes, gt_labels,
                                       gt_bboxes, mask_gt, fg_cnt, fg_m);

    int nA = BS * NA;
    k_assign<<<(nA + 255) / 256, 256, 0, stream>>>(
        pd_scores, pd_bboxes, anc, gt_labels, gt_bboxes, mask_gt,
        fg_cnt, fg_m, out, am_ws, gi_ws, lbl_ws, pos_am, pos_ov,
        multi_cnt, multi_q, fgq_cnt, fgq);

    // ~23K multi-assigned anchors observed; one wave each -> need thousands of
    // waves in flight. 2048 blocks x 4 waves = 8192 waves (~3 iters/wave).
    k_fix<<<2048, 256, 0, stream>>>(
        pd_scores, pd_bboxes, anc, gt_labels, gt_bboxes, mask_gt,
        multi_cnt, multi_q, out, am_ws, gi_ws, lbl_ws, pos_am, pos_ov,
        fgq_cnt, fgq);

    k_scatter<<<256, 256, 0, stream>>>(fgq_cnt, fgq, am_ws, gi_ws, lbl_ws,
                                       pos_am, pos_ov, out + OFF_SC);
}

// Round 5
// 152.848 us; speedup vs baseline: 1.5032x; 1.4717x over previous
//
#include <hip/hip_runtime.h>
#include <math.h>

// Problem constants (fixed by setup_inputs)
constexpr int BS = 16;
constexpr int NA = 8400;    // 80^2 + 40^2 + 20^2, strides 8/16/32
constexpr int NC = 80;
constexpr int MG = 128;
constexpr int TK = 13;
constexpr int NCAND = 1536; // max enumerated inside-candidates ~1251 (box<200^2)
constexpr int QCAP = 65536; // multi queue (observed ~23K)

// Output layout (floats), return order: labels, bboxes, scores, fg_mask, tgt_idx
constexpr int OFF_LBL = 0;
constexpr int OFF_BB  = OFF_LBL + BS * NA;
constexpr int OFF_SC  = OFF_BB  + BS * NA * 4;
constexpr int OFF_FG  = OFF_SC  + BS * NA * NC;
constexpr int OFF_TG  = OFF_FG  + BS * NA;

// CIoU with the arctan difference supplied by the caller (hot loops hoist the
// loop-invariant atanf). dat = atanf(w2/h2) - atanf(w1/h1).
__device__ __forceinline__ float ciou_pre(float gx, float gy, float gz, float gw,
                                          float px, float py, float pz, float pw,
                                          float dat) {
    const float eps = 1e-7f;
    float w1 = gz - gx, h1 = gw - gy + eps;
    float w2 = pz - px, h2 = pw - py + eps;
    float iw = fmaxf(fminf(gz, pz) - fmaxf(gx, px), 0.f);
    float ih = fmaxf(fminf(gw, pw) - fmaxf(gy, py), 0.f);
    float inter = iw * ih;
    float uni = w1 * h1 + w2 * h2 - inter + eps;
    float iou = inter / uni;
    float cw = fmaxf(gz, pz) - fminf(gx, px);
    float ch = fmaxf(gw, pw) - fminf(gy, py);
    float c2 = cw * cw + ch * ch + eps;
    float dx = px + pz - gx - gz;
    float dy = py + pw - gy - gw;
    float rho2 = (dx * dx + dy * dy) * 0.25f;
    float v = 0.4052847345693511f * dat * dat;   // 4/pi^2
    float alpha = v / (v - iou + (1.f + eps));
    return iou - (rho2 / c2 + v * alpha);
}

__device__ __forceinline__ float ciou_f(float gx, float gy, float gz, float gw,
                                        float px, float py, float pz, float pw) {
    const float eps = 1e-7f;
    float dat = atanf((pz - px) / (pw - py + eps)) - atanf((gz - gx) / (gw - gy + eps));
    return ciou_pre(gx, gy, gz, gw, px, py, pz, pw, dat);
}

__device__ __forceinline__ bool inside_gt(float ax, float ay,
                                          float gx, float gy, float gz, float gw) {
    float d = fminf(fminf(ax - gx, ay - gy), fminf(gz - ax, gw - ay));
    return d > 1e-9f;
}

// anchor index -> grid-point coords, bitwise == anc[] ((i+0.5)*s, s pow2)
__device__ __forceinline__ void anchor_xy(int a, float& ax, float& ay) {
    if (a < 6400)      { int iy = a / 80;        int ix = a - iy * 80 - 0;    ax = (ix + 0.5f) * 8.f;  ay = (iy + 0.5f) * 8.f; }
    else if (a < 8000) { int r = a - 6400; int iy = r / 40; int ix = r - iy * 40; ax = (ix + 0.5f) * 16.f; ay = (iy + 0.5f) * 16.f; }
    else               { int r = a - 8000; int iy = r / 20; int ix = r - iy * 20; ax = (ix + 0.5f) * 32.f; ay = (iy + 0.5f) * 32.f; }
}

// K1: one WAVE per (b,m). Enumerate candidate anchors from the box's grid
// rectangles (3 levels), compact positives to LDS, 13 shuffle-argmax rounds
// (exact lax.top_k semantics: lowest-index ties + npos<13 zero-fill).
__global__ __launch_bounds__(64) void k_topk(
    const float* __restrict__ pd_scores, const float* __restrict__ pd_bboxes,
    const int* __restrict__ gt_labels, const float* __restrict__ gt_bboxes,
    const float* __restrict__ mask_gt,
    int* __restrict__ fg_cnt, int* __restrict__ fg_m)
{
    __shared__ float cv[NCAND];
    __shared__ int   ca[NCAND];
    __shared__ int   s_cnt;
    __shared__ unsigned s_pm;           // "align>0" mask for anchors 0..31

    int bm = blockIdx.x;
    if (mask_gt[bm] <= 0.f) return;
    int b = bm >> 7;                    // MG = 128
    int m = bm & (MG - 1);
    int tid = threadIdx.x;

    if (tid == 0) { s_cnt = 0; s_pm = 0u; }
    __syncthreads();

    const float4 g = *reinterpret_cast<const float4*>(gt_bboxes + bm * 4);
    const int lbl = gt_labels[bm];
    const float* pbb = pd_bboxes + (size_t)b * NA * 4;
    const float* psc = pd_scores + (size_t)b * NA * NC;
    const float at_g = atanf((g.z - g.x) / (g.w - g.y + 1e-7f));  // block-invariant

    auto do_level = [&](float s, int n, int base) {
        // conservative rectangle (+-1 cell); exact inside_gt per candidate
        // keeps the positive set bitwise-identical.
        int xlo = max(0, (int)floorf(g.x / s - 0.5f) - 1);
        int xhi = min(n - 1, (int)ceilf(g.z / s - 0.5f) + 1);
        int ylo = max(0, (int)floorf(g.y / s - 0.5f) - 1);
        int yhi = min(n - 1, (int)ceilf(g.w / s - 0.5f) + 1);
        int w = xhi - xlo + 1, h = yhi - ylo + 1;
        if (w <= 0 || h <= 0) return;
        int cnt = w * h;
        for (int idx = tid; idx < cnt; idx += 64) {
            int iy = ylo + idx / w;
            int ix = xlo + idx - (idx / w) * w;
            float ax = (ix + 0.5f) * s;
            float ay = (iy + 0.5f) * s;
            if (!inside_gt(ax, ay, g.x, g.y, g.z, g.w)) continue;
            int a = base + iy * n + ix;
            float4 p = *reinterpret_cast<const float4*>(pbb + (size_t)a * 4);
            float dat = atanf((p.z - p.x) / (p.w - p.y + 1e-7f)) - at_g;
            float ov = fmaxf(ciou_pre(g.x, g.y, g.z, g.w, p.x, p.y, p.z, p.w, dat), 0.f);
            float sc = psc[(size_t)a * NC + lbl];
            float ov2 = ov * ov;
            float al = sc * ov2 * ov2 * ov2;     // score^1 * ov^6
            if (al > 0.f) {
                int slot = atomicAdd(&s_cnt, 1);
                if (slot < NCAND) { cv[slot] = al; ca[slot] = a; }
                if (a < 32) atomicOr(&s_pm, 1u << a);
            }
        }
    };
    do_level(8.f, 80, 0);
    do_level(16.f, 40, 6400);
    do_level(32.f, 20, 8000);
    __syncthreads();

    int npos = min(s_cnt, NCAND);
    int rounds = min(npos, TK);
    int* fgc = fg_cnt + b * NA;
    int* fgm = fg_m + b * NA;

    for (int k = 0; k < rounds; ++k) {
        float bv = -1.f; int bk = 0x7fffffff;
        for (int p = tid; p < npos; p += 64) {
            float v = cv[p];
            int key = (ca[p] << 11) | p;         // anchor high bits: ties -> lowest anchor
            if (v > bv || (v == bv && key < bk)) { bv = v; bk = key; }
        }
        #pragma unroll
        for (int off = 32; off > 0; off >>= 1) {
            float v2 = __shfl_down(bv, off);
            int   k2 = __shfl_down(bk, off);
            if (v2 > bv || (v2 == bv && k2 < bk)) { bv = v2; bk = k2; }
        }
        if (tid == 0) {
            int slot = bk & 2047;
            int a = bk >> 11;
            cv[slot] = -1.f;                     // remove winner
            atomicAdd(&fgc[a], 1);
            fgm[a] = m;                          // unique writer when final cnt==1
        }
        __syncthreads();
    }

    // npos < TK: top_k pads with globally lowest-index zero-valued anchors
    // (indices provably < 26 < 32); mask_in_gts then filters them.
    if (tid == 0) {
        int need = TK - rounds;
        unsigned pm = s_pm;
        for (int idx = 0; idx < 32 && need > 0; ++idx) {
            if (!((pm >> idx) & 1u)) {
                float ax = (idx + 0.5f) * 8.f, ay = 4.f;
                if (inside_gt(ax, ay, g.x, g.y, g.z, g.w)) {
                    atomicAdd(&fgc[idx], 1);
                    fgm[idx] = m;
                }
                --need;
            }
        }
    }
}

// K2: per anchor. cnt<=1 resolved inline; cnt>1 appended to multi_q via
// wave-ballot compaction + one global atomicAdd per block (no hot-address
// atomic streams). 134400 = 525*256, so every block is full.
__global__ __launch_bounds__(256) void k_assign(
    const float* __restrict__ pd_scores, const float* __restrict__ pd_bboxes,
    const int* __restrict__ gt_labels, const float* __restrict__ gt_bboxes,
    const float* __restrict__ mask_gt,
    const int* __restrict__ fg_cnt, const int* __restrict__ fg_m,
    float* __restrict__ out, float* __restrict__ am_ws,
    int* __restrict__ gi_ws, int* __restrict__ lbl_ws,
    unsigned* __restrict__ pos_am, unsigned* __restrict__ pos_ov,
    int* __restrict__ multi_cnt, int* __restrict__ multi_q)
{
    __shared__ int s_cnt, s_base;
    int tid = threadIdx.x;
    if (tid == 0) s_cnt = 0;
    __syncthreads();

    int i = blockIdx.x * 256 + tid;
    int cnt = fg_cnt[i];
    bool multi = cnt > 1;

    // wave-level compaction of multi-anchors
    unsigned long long mk = __ballot(multi);
    int lane = tid & 63;
    int rank = __popcll(mk & ((1ull << lane) - 1ull));
    int wsum = __popcll(mk);
    int wbase = 0;
    if (lane == 0 && wsum) wbase = atomicAdd(&s_cnt, wsum);
    wbase = __shfl(wbase, 0);
    __syncthreads();
    if (tid == 0 && s_cnt) s_base = atomicAdd(multi_cnt, s_cnt);
    __syncthreads();

    if (multi) {
        multi_q[s_base + wbase + rank] = i;      // outputs written by k_fix
        return;
    }

    int b = i / NA, a = i - b * NA;
    int t = (cnt == 1) ? fg_m[i] : 0;
    int gi = b * MG + t;
    float4 g = *reinterpret_cast<const float4*>(gt_bboxes + gi * 4);
    int lraw = gt_labels[gi];
    int lbl = max(lraw, 0);

    if (cnt == 1) {
        float am = 0.f, ovv = 0.f;
        if (mask_gt[gi] > 0.f) {
            float ax, ay; anchor_xy(a, ax, ay);
            if (inside_gt(ax, ay, g.x, g.y, g.z, g.w)) {
                float4 p = *reinterpret_cast<const float4*>(pd_bboxes + (size_t)i * 4);
                float ov = fmaxf(ciou_f(g.x, g.y, g.z, g.w, p.x, p.y, p.z, p.w), 0.f);
                float sc = pd_scores[(size_t)i * NC + lraw];
                float ov2 = ov * ov;
                am = sc * ov2 * ov2 * ov2;
                ovv = ov;
            }
        }
        atomicMax(&pos_am[gi], __float_as_uint(am));
        atomicMax(&pos_ov[gi], __float_as_uint(ovv));
        am_ws[i] = am; gi_ws[i] = gi; lbl_ws[i] = lbl;
    } else {
        gi_ws[i] = -1;                           // background: no score scatter
    }

    out[OFF_LBL + i] = (float)lbl;
    reinterpret_cast<float4*>(out + OFF_BB)[i] = g;
    out[OFF_FG + i] = cnt ? 1.f : 0.f;
    out[OFF_TG + i] = (float)t;
}

// K3: one wave per multi-assigned anchor — argmax over 128 masked overlaps
// (2 per lane + shuffle reduce, first-max tie-break), write its outputs.
__global__ __launch_bounds__(256) void k_fix(
    const float* __restrict__ pd_scores, const float* __restrict__ pd_bboxes,
    const int* __restrict__ gt_labels, const float* __restrict__ gt_bboxes,
    const float* __restrict__ mask_gt,
    const int* __restrict__ multi_cnt, const int* __restrict__ multi_q,
    float* __restrict__ out, float* __restrict__ am_ws,
    int* __restrict__ gi_ws, int* __restrict__ lbl_ws,
    unsigned* __restrict__ pos_am, unsigned* __restrict__ pos_ov)
{
    int gtid = blockIdx.x * 256 + threadIdx.x;
    int wave = gtid >> 6;
    int lane = gtid & 63;
    int nwaves = (gridDim.x * 256) >> 6;
    int qn = *multi_cnt;

    for (int qi = wave; qi < qn; qi += nwaves) {
        int i = multi_q[qi];
        int b = i / NA, a = i - b * NA;
        float ax, ay; anchor_xy(a, ax, ay);
        float4 p = *reinterpret_cast<const float4*>(pd_bboxes + (size_t)i * 4);
        float at_p = atanf((p.z - p.x) / (p.w - p.y + 1e-7f));  // anchor-invariant

        auto ovm = [&](int mm) -> float {
            int gi = b * MG + mm;
            float ov = 0.f;
            if (mask_gt[gi] > 0.f) {
                float4 gg = *reinterpret_cast<const float4*>(gt_bboxes + gi * 4);
                if (inside_gt(ax, ay, gg.x, gg.y, gg.z, gg.w)) {
                    float dat = at_p - atanf((gg.z - gg.x) / (gg.w - gg.y + 1e-7f));
                    ov = fmaxf(ciou_pre(gg.x, gg.y, gg.z, gg.w, p.x, p.y, p.z, p.w, dat), 0.f);
                }
            }
            return ov;
        };
        float ov0 = ovm(lane);
        float ov1 = ovm(lane + 64);
        float bov; int bm_;
        if (ov1 > ov0) { bov = ov1; bm_ = lane + 64; }
        else           { bov = ov0; bm_ = lane; }
        #pragma unroll
        for (int off = 32; off > 0; off >>= 1) {
            float v2 = __shfl_down(bov, off);
            int   m2 = __shfl_down(bm_, off);
            if (v2 > bov || (v2 == bov && m2 < bm_)) { bov = v2; bm_ = m2; }
        }
        if (lane == 0) {
            int t = bm_;
            int gi = b * MG + t;
            int lraw = gt_labels[gi];
            int lbl = max(lraw, 0);
            float am = 0.f;
            if (bov > 0.f) {                     // bov>0 implies mask&&inside at t
                float sc = pd_scores[(size_t)i * NC + lraw];
                float o2 = bov * bov;
                am = sc * o2 * o2 * o2;
            }
            atomicMax(&pos_am[gi], __float_as_uint(am));
            atomicMax(&pos_ov[gi], __float_as_uint(bov));
            float4 g = *reinterpret_cast<const float4*>(gt_bboxes + gi * 4);
            out[OFF_LBL + i] = (float)lbl;
            reinterpret_cast<float4*>(out + OFF_BB)[i] = g;
            out[OFF_FG + i] = 1.f;
            out[OFF_TG + i] = (float)t;
            am_ws[i] = am; gi_ws[i] = gi; lbl_ws[i] = lbl;
        }
    }
}

// K4: scatter norm into the (pre-zeroed) scores tensor — scan gi_ws, one 4B
// store per fg anchor. No queue, no hot atomics.
__global__ __launch_bounds__(256) void k_scatter(
    const float* __restrict__ am_ws, const int* __restrict__ gi_ws,
    const int* __restrict__ lbl_ws,
    const unsigned* __restrict__ pos_am, const unsigned* __restrict__ pos_ov,
    float* __restrict__ out_scores)
{
    int i = blockIdx.x * 256 + threadIdx.x;
    if (i >= BS * NA) return;
    int gi = gi_ws[i];
    if (gi >= 0) {
        float norm = am_ws[i] * __uint_as_float(pos_ov[gi]) /
                     (__uint_as_float(pos_am[gi]) + 1e-9f);
        out_scores[(size_t)i * NC + lbl_ws[i]] = norm;
    }
}

extern "C" void kernel_launch(void* const* d_in, const int* in_sizes, int n_in,
                              void* d_out, int out_size, void* d_ws, size_t ws_size,
                              hipStream_t stream) {
    const float* pd_scores = (const float*)d_in[0];
    const float* pd_bboxes = (const float*)d_in[1];
    const int*   gt_labels = (const int*)d_in[3];
    const float* gt_bboxes = (const float*)d_in[4];
    const float* mask_gt   = (const float*)d_in[5];
    float* out = (float*)d_out;

    // Workspace carve. Zeroed region first.
    unsigned char* w = (unsigned char*)d_ws;
    size_t off = 0;
    int*      fg_cnt    = (int*)(w + off);      off += (size_t)BS * NA * 4;
    unsigned* pos_am    = (unsigned*)(w + off); off += (size_t)BS * MG * 4;
    unsigned* pos_ov    = (unsigned*)(w + off); off += (size_t)BS * MG * 4;
    int*      multi_cnt = (int*)(w + off);      off += 4;
    size_t zero_bytes = off;
    int*      fg_m      = (int*)(w + off);      off += (size_t)BS * NA * 4;
    float*    am_ws     = (float*)(w + off);    off += (size_t)BS * NA * 4;
    int*      gi_ws     = (int*)(w + off);      off += (size_t)BS * NA * 4;
    int*      lbl_ws    = (int*)(w + off);      off += (size_t)BS * NA * 4;
    int*      multi_q   = (int*)(w + off);      off += (size_t)QCAP * 4;

    hipMemsetAsync(w, 0, zero_bytes, stream);
    hipMemsetAsync(out + OFF_SC, 0, (size_t)BS * NA * NC * sizeof(float), stream);

    k_topk<<<BS * MG, 64, 0, stream>>>(pd_scores, pd_bboxes, gt_labels,
                                       gt_bboxes, mask_gt, fg_cnt, fg_m);

    int nA = BS * NA;                            // 134400 = 525 * 256
    k_assign<<<nA / 256, 256, 0, stream>>>(
        pd_scores, pd_bboxes, gt_labels, gt_bboxes, mask_gt,
        fg_cnt, fg_m, out, am_ws, gi_ws, lbl_ws, pos_am, pos_ov,
        multi_cnt, multi_q);

    // ~23K multi anchors, one wave each: 2048 blocks x 4 waves = 8192 waves.
    k_fix<<<2048, 256, 0, stream>>>(
        pd_scores, pd_bboxes, gt_labels, gt_bboxes, mask_gt,
        multi_cnt, multi_q, out, am_ws, gi_ws, lbl_ws, pos_am, pos_ov);

    k_scatter<<<nA / 256, 256, 0, stream>>>(am_ws, gi_ws, lbl_ws,
                                            pos_am, pos_ov, out + OFF_SC);
}